// Round 18
// baseline (145.371 us; speedup 1.0000x reference)
//
#include <hip/hip_runtime.h>
#include <hip/hip_bf16.h>

typedef __attribute__((ext_vector_type(8))) short short8;
typedef __attribute__((ext_vector_type(4))) float floatx4;

#define L2E 1.4426950408889634f

#if __has_builtin(__builtin_amdgcn_exp2f)
#define EXP2(x) __builtin_amdgcn_exp2f(x)
#else
#define EXP2(x) exp2f(x)
#endif
#if __has_builtin(__builtin_amdgcn_rcpf)
#define RCP(x) __builtin_amdgcn_rcpf(x)
#else
#define RCP(x) (1.0f / (x))
#endif

static __device__ __forceinline__ unsigned short f2bf(float f) {
    unsigned int u = __builtin_bit_cast(unsigned int, f);
    u += 0x7fffu + ((u >> 16) & 1u);   // RNE
    return (unsigned short)(u >> 16);
}
static __device__ __forceinline__ unsigned int pk_bf16(float a, float b) {
    __hip_bfloat162 h2 = __float22bfloat162_rn(make_float2(a, b));   // v_cvt_pk_bf16_f32
    unsigned int u;
    __builtin_memcpy(&u, &h2, 4);     // low16 = a, high16 = b
    return u;
}

// ---------------- 1) QKV GEMM (R25 verbatim: vectorized staging, LDS-bounced V^T) ----------------
__global__ __launch_bounds__(256) void k_qkv(const float* __restrict__ x,
                                             const float* __restrict__ qw,
                                             unsigned short* __restrict__ qm,
                                             unsigned short* __restrict__ km,
                                             unsigned short* __restrict__ vt) {
    __shared__ __align__(16) unsigned short At[64][136];
    __shared__ __align__(16) unsigned short Wt[64][136];
    const int tid = threadIdx.x;
    const int wave = tid >> 6, lane = tid & 63;
    const int l16 = lane & 15, quad = lane >> 4;
    const int m0 = blockIdx.x * 64;
    const int o0 = blockIdx.y * 64;

    floatx4 acc[4] = {};
    for (int rnd = 0; rnd < 2; ++rnd) {
        const int cbase = rnd * 128;
        if (rnd) __syncthreads();
        {
            const int tok0 = (tid & 15) * 4;
            const int c0   = (tid >> 4) * 8;
            const float* xp = x + (size_t)(cbase + c0) * 4096 + m0 + tok0;
            float4 v[8];
            #pragma unroll
            for (int j = 0; j < 8; ++j)
                v[j] = *reinterpret_cast<const float4*>(xp + (size_t)j * 4096);
            #pragma unroll
            for (int t = 0; t < 4; ++t) {
                unsigned int d[4];
                d[0] = pk_bf16((&v[0].x)[t], (&v[1].x)[t]);
                d[1] = pk_bf16((&v[2].x)[t], (&v[3].x)[t]);
                d[2] = pk_bf16((&v[4].x)[t], (&v[5].x)[t]);
                d[3] = pk_bf16((&v[6].x)[t], (&v[7].x)[t]);
                __builtin_memcpy(&At[tok0 + t][c0], d, 16);
            }
        }
        {
            const int o_l = tid >> 2, cp = (tid & 3) * 32;
            const float4* wp = reinterpret_cast<const float4*>(
                qw + (size_t)(o0 + o_l) * 256 + cbase + cp);
            #pragma unroll
            for (int j = 0; j < 2; ++j) {
                const float4 g0 = wp[4 * j + 0], g1 = wp[4 * j + 1];
                const float4 g2 = wp[4 * j + 2], g3 = wp[4 * j + 3];
                unsigned int u[8];
                u[0] = pk_bf16(g0.x, g0.y); u[1] = pk_bf16(g0.z, g0.w);
                u[2] = pk_bf16(g1.x, g1.y); u[3] = pk_bf16(g1.z, g1.w);
                u[4] = pk_bf16(g2.x, g2.y); u[5] = pk_bf16(g2.z, g2.w);
                u[6] = pk_bf16(g3.x, g3.y); u[7] = pk_bf16(g3.z, g3.w);
                __builtin_memcpy(&Wt[o_l][cp + 16 * j], u, 32);
            }
        }
        __syncthreads();
        #pragma unroll
        for (int cc = 0; cc < 4; ++cc) {
            const int c0 = cc * 32 + quad * 8;
            const short8 a = *reinterpret_cast<const short8*>(&At[wave * 16 + l16][c0]);
            #pragma unroll
            for (int t4 = 0; t4 < 4; ++t4) {
                const short8 b = *reinterpret_cast<const short8*>(&Wt[t4 * 16 + l16][c0]);
                acc[t4] = __builtin_amdgcn_mfma_f32_16x16x32_bf16(a, b, acc[t4], 0, 0, 0);
            }
        }
    }

    const int s = o0 >> 8;   // block-uniform: 0=q, 1=k, 2=v
    if (s < 2) {
        const float qscale = 0.17677669529663687f * L2E;
        #pragma unroll
        for (int t4 = 0; t4 < 4; ++t4) {
            #pragma unroll
            for (int r = 0; r < 4; ++r) {
                const int n = m0 + wave * 16 + quad * 4 + r;
                const int o = o0 + t4 * 16 + l16;
                const int rem = o & 255, head = rem >> 5, t = rem & 31;
                if (s == 0)  qm[((size_t)head * 4096 + n) * 32 + t] = f2bf(acc[t4][r] * qscale);
                else         km[((size_t)head * 4096 + n) * 32 + t] = f2bf(acc[t4][r]);
            }
        }
    } else {
        __syncthreads();
        unsigned short (*Ct)[72] = reinterpret_cast<unsigned short(*)[72]>(&At[0][0]);
        #pragma unroll
        for (int t4 = 0; t4 < 4; ++t4) {
            unsigned int d2[2];
            d2[0] = pk_bf16(acc[t4][0], acc[t4][1]);
            d2[1] = pk_bf16(acc[t4][2], acc[t4][3]);
            __builtin_memcpy(&Ct[t4 * 16 + l16][wave * 16 + quad * 4], d2, 8);
        }
        __syncthreads();
        const int row = tid >> 2, col0 = (tid & 3) * 16;
        unsigned short* dst = vt + (size_t)(o0 - 512 + row) * 4096 + m0 + col0;
        const short8 ca = *reinterpret_cast<const short8*>(&Ct[row][col0]);
        const short8 cb = *reinterpret_cast<const short8*>(&Ct[row][col0 + 8]);
        *reinterpret_cast<short8*>(dst) = ca;
        *reinterpret_cast<short8*>(dst + 8) = cb;
    }
}

// ---------------- 2) flash attention: KV-window split (2 halves/block-pair) + f32 atomic combine ----------------
// R33: R32 hit its falsifier -- removing 15% of work moved time 1% (stall-dominated
// phases), and no pipe is >40% busy. Binding constraint is PARALLELISM: grid 512 =
// exactly 2 blocks/CU, no queue, no backfill for the NT=40..64 imbalance. This
// round splits each block's key-window in half: 1024 blocks (blockIdx.x = qblk*2 +
// half), each runs the SAME 2-chain phase structure over T in [half*NT/2,
// (half+1)*NT/2) -- half the lifetime. LDS 51200 -> 3 blocks/CU resident, 256
// queued -> backfill smooths imbalance; 12 waves/CU hides the chain latency.
// Combine: accumulate UNNORMALIZED O and l into f32 via unsafeAtomicAdd (device-
// scope HW f32 atomics, order-free); k_proj divides by l when building its
// B-fragment (same math + rounding point as before). hipMemsetAsync zeroes the
// accumulators each launch.
__global__ __launch_bounds__(256, 2) void k_attn(const unsigned short* __restrict__ qm,
                                                 const unsigned short* __restrict__ km,
                                                 const unsigned short* __restrict__ vt,
                                                 float* __restrict__ of32,
                                                 float* __restrict__ lsum) {
    const int h    = blockIdx.y;
    const int half = blockIdx.x & 1;
    const int nq0  = (blockIdx.x >> 1) * 64;  // 64 q-rows per block (same dq for all)
    const int tid = threadIdx.x;
    const int wv  = tid >> 6;                 // wave owns q-tile nq0 + wv*16
    const int lane = tid & 63;
    const int l16 = lane & 15, quad = lane >> 4;
    const int nqw = nq0 + wv * 16;

    __shared__ __align__(16) unsigned short Kt[2][2][2048];   // [buf][slot][key*32+dim ^ swz]
    __shared__ __align__(16) unsigned short Vt[2][2][2048];   // [buf][slot][kg*256+dim*8 ^ swz]
    __shared__ __align__(16) unsigned short PT[4][2][16][72]; // [wave][slot][q][key] plain

    const short8 a_q = *reinterpret_cast<const short8*>(
        qm + ((size_t)h * 4096 + nqw + l16) * 32 + quad * 8);

    const int hq = (nqw >> 4) & 15;
    const int dq = nq0 >> 8;
    float dw2[4];
    #pragma unroll
    for (int r = 0; r < 4; ++r) {
        const float dw = (float)(quad * 4 + r - l16);
        dw2[r] = dw * dw;
    }

    const int dk_lo = (dq > 9) ? dq - 9 : 0;
    const int dk_hi = (dq < 6) ? dq + 9 : 15;
    const int NT  = 4 * (dk_hi - dk_lo + 1);  // 40..64, divisible by 4
    const int NTh = NT >> 1;                  // even, >= 20
    const int T0 = half * NTh, T1 = T0 + NTh;

    const int skey = tid >> 2;
    const int sdo  = (tid & 3) * 8;
    const int sdim = tid >> 3;
    const int skg  = tid & 7;
    const unsigned short* ksrc = km + ((size_t)h << 17) + skey * 32 + sdo;
    const unsigned short* vsrc = vt + (((size_t)h * 32 + sdim) << 12) + skg * 8;
    const int kdst = (skey * 32 + sdo) ^ ((skey & 7) << 3);
    const int vdst = (skg * 256 + sdim * 8) ^ (skg << 3);

    float l_acc = 0.f;
    floatx4 o_acc[2][2] = {};                 // [slot][hf]

#define J0T(T) (((dk_lo + ((T) >> 2)) << 8) + (((T) & 3) << 6))

    short8 rK[2], rV[2];
#define LOAD2(TA, TB) {                                                   \
        const int ja_ = J0T(TA), jb_ = J0T(TB);                           \
        rK[0] = *reinterpret_cast<const short8*>(ksrc + (size_t)ja_ * 32);\
        rV[0] = *reinterpret_cast<const short8*>(vsrc + ja_);             \
        rK[1] = *reinterpret_cast<const short8*>(ksrc + (size_t)jb_ * 32);\
        rV[1] = *reinterpret_cast<const short8*>(vsrc + jb_);             \
    }
#define WRITE2(NB) {                                                      \
        *reinterpret_cast<short8*>(&Kt[NB][0][kdst]) = rK[0];             \
        *reinterpret_cast<short8*>(&Vt[NB][0][vdst]) = rV[0];             \
        *reinterpret_cast<short8*>(&Kt[NB][1][kdst]) = rK[1];             \
        *reinterpret_cast<short8*>(&Vt[NB][1][vdst]) = rV[1];             \
    }

// scalar thresholds for tile T (SALU; wave-uniform)
#define THR(T, TH) {                                                      \
        const int dk_ = dk_lo + ((T) >> 2), g_ = (T) & 3;                 \
        const int dd_ = dq - dk_;                                         \
        const int bb_ = 100 - dd_ * dd_;                                  \
        const int h0_ = hq - 4 * g_;                                      \
        TH[0] = bb_ - h0_ * h0_;                                          \
        TH[1] = bb_ - (h0_ - 1) * (h0_ - 1);                              \
        TH[2] = bb_ - (h0_ - 2) * (h0_ - 2);                              \
        TH[3] = bb_ - (h0_ - 3) * (h0_ - 3);                              \
    }

// branch-free S stage with precomputed thresholds (dead subtiles -> exact P=0)
#define SSTAGE(TH, CB, SL) {                                              \
        _Pragma("unroll")                                                 \
        for (int t4 = 0; t4 < 4; ++t4) {                                  \
            const short8 kf = *reinterpret_cast<const short8*>(           \
                &Kt[CB][SL][((t4 * 16 + l16) * 32 + quad * 8) ^ ((l16 & 7) << 3)]); \
            const floatx4 sf = __builtin_amdgcn_mfma_f32_16x16x32_bf16(   \
                kf, a_q, (floatx4){0.f, 0.f, 0.f, 0.f}, 0, 0, 0);         \
            const float thrf = (float)TH[t4];                             \
            const float p0 = (dw2[0] < thrf) ? EXP2(sf[0]) : 0.f;         \
            const float p1 = (dw2[1] < thrf) ? EXP2(sf[1]) : 0.f;         \
            const float p2 = (dw2[2] < thrf) ? EXP2(sf[2]) : 0.f;         \
            const float p3 = (dw2[3] < thrf) ? EXP2(sf[3]) : 0.f;         \
            l_acc += (p0 + p1) + (p2 + p3);                               \
            unsigned int pair_[2];                                        \
            pair_[0] = pk_bf16(p0, p1);                                   \
            pair_[1] = pk_bf16(p2, p3);                                   \
            __builtin_memcpy(&PT[wv][SL][l16][t4 * 16 + quad * 4], pair_, 8); \
        }                                                                 \
    }

#define PVST(CB, SL) {                                                    \
        _Pragma("unroll")                                                 \
        for (int kt = 0; kt < 2; ++kt) {                                  \
            const short8 b_p = *reinterpret_cast<const short8*>(          \
                &PT[wv][SL][l16][kt * 32 + quad * 8]);                    \
            const int kg = kt * 4 + quad;                                 \
            _Pragma("unroll")                                             \
            for (int hf = 0; hf < 2; ++hf) {                              \
                const short8 vf = *reinterpret_cast<const short8*>(       \
                    &Vt[CB][SL][(kg * 256 + (hf * 16 + l16) * 8) ^ (kg << 3)]); \
                o_acc[SL][hf] = __builtin_amdgcn_mfma_f32_16x16x32_bf16(  \
                    vf, b_p, o_acc[SL][hf], 0, 0, 0);                     \
            }                                                             \
        }                                                                 \
    }

    // prologue: tiles T0,T0+1 -> buf0; tiles T0+2,T0+3 -> regs (NTh >= 20)
    LOAD2(T0, T0 + 1)
    WRITE2(0)
    LOAD2(T0 + 2, T0 + 3)
    __syncthreads();

    for (int t2 = T0; t2 < T1; t2 += 2) {
        const int cb = ((t2 - T0) >> 1) & 1, nb = cb ^ 1;
        WRITE2(nb)                      // tiles t2+2, t2+3 (vmcnt waits here)
        {
            int ta = t2 + 4; if (ta >= T1) ta = T1 - 1;
            int tb = t2 + 5; if (tb >= T1) tb = T1 - 1;
            LOAD2(ta, tb)               // issue early; consumed next phase
        }
        int thA[4], thB[4];
        THR(t2, thA)
        THR(t2 + 1, thB)
        const bool liveA = (thA[0] > 0) | (thA[1] > 0) | (thA[2] > 0) | (thA[3] > 0);
        const bool liveB = (thB[0] > 0) | (thB[1] > 0) | (thB[2] > 0) | (thB[3] > 0);
        __builtin_amdgcn_s_setprio(1);  // T5: compute section wins SIMD arbitration
        if (liveA & liveB) {            // fast path: measured straight-line block
            SSTAGE(thA, cb, 0)
            SSTAGE(thB, cb, 1)
            PVST(cb, 0)
            PVST(cb, 1)
        } else if (liveA) {
            SSTAGE(thA, cb, 0)
            PVST(cb, 0)
        } else if (liveB) {
            SSTAGE(thB, cb, 1)
            PVST(cb, 1)
        }
        __builtin_amdgcn_s_setprio(0);
        __syncthreads();
    }
#undef PVST
#undef SSTAGE
#undef THR
#undef WRITE2
#undef LOAD2
#undef J0T

    // epilogue: accumulate UNNORMALIZED partials (f32 atomics, order-free)
    l_acc += __shfl_xor(l_acc, 16);
    l_acc += __shfl_xor(l_acc, 32);
    #pragma unroll
    for (int hf = 0; hf < 2; ++hf) {
        const floatx4 os = o_acc[0][hf] + o_acc[1][hf];
        float* op = of32 + (size_t)(nqw + l16) * 256 + h * 32 + hf * 16 + quad * 4;
        unsafeAtomicAdd(op + 0, os[0]);
        unsafeAtomicAdd(op + 1, os[1]);
        unsafeAtomicAdd(op + 2, os[2]);
        unsafeAtomicAdd(op + 3, os[3]);
    }
    if (lane < 16) unsafeAtomicAdd(lsum + (size_t)h * 4096 + nqw + l16, l_acc);
}

// ---------------- 3) proj GEMM + bias: reads f32 partials, normalizes in B-fragment build ----------------
__global__ __launch_bounds__(256) void k_proj(const float* __restrict__ of32,
                                              const float* __restrict__ lsum,
                                              const float* __restrict__ pw,
                                              const float* __restrict__ pb,
                                              float* __restrict__ out) {
    __shared__ __align__(16) unsigned short Pt[64][264];
    const int tid = threadIdx.x;
    const int wave = tid >> 6, lane = tid & 63;
    const int l16 = lane & 15, quad = lane >> 4;
    const int n0 = blockIdx.x * 32;
    const int m0 = blockIdx.y * 64;

    {
        const int o_l = tid >> 2, cp = (tid & 3) * 64;
        const float4* wp = reinterpret_cast<const float4*>(pw + (size_t)(m0 + o_l) * 256 + cp);
        #pragma unroll
        for (int j = 0; j < 4; ++j) {
            const float4 g0 = wp[4 * j + 0], g1 = wp[4 * j + 1];
            const float4 g2 = wp[4 * j + 2], g3 = wp[4 * j + 3];
            unsigned int u[8];
            u[0] = pk_bf16(g0.x, g0.y); u[1] = pk_bf16(g0.z, g0.w);
            u[2] = pk_bf16(g1.x, g1.y); u[3] = pk_bf16(g1.z, g1.w);
            u[4] = pk_bf16(g2.x, g2.y); u[5] = pk_bf16(g2.z, g2.w);
            u[6] = pk_bf16(g3.x, g3.y); u[7] = pk_bf16(g3.z, g3.w);
            __builtin_memcpy(&Pt[o_l][cp + 16 * j], u, 32);
        }
    }
    __syncthreads();

    floatx4 acc[2] = {};
    #pragma unroll
    for (int cc = 0; cc < 8; ++cc) {
        const int c0 = cc * 32 + quad * 8;
        const short8 a = *reinterpret_cast<const short8*>(&Pt[wave * 16 + l16][c0]);
        #pragma unroll
        for (int t4 = 0; t4 < 2; ++t4) {
            const int n = n0 + t4 * 16 + l16;
            const float* op = of32 + (size_t)n * 256 + c0;   // head = cc (quad*8 < 32)
            const float4 f0 = *reinterpret_cast<const float4*>(op);
            const float4 f1 = *reinterpret_cast<const float4*>(op + 4);
            const float inv = RCP(lsum[(size_t)cc * 4096 + n]);
            unsigned int bw[4];
            bw[0] = pk_bf16(f0.x * inv, f0.y * inv);
            bw[1] = pk_bf16(f0.z * inv, f0.w * inv);
            bw[2] = pk_bf16(f1.x * inv, f1.y * inv);
            bw[3] = pk_bf16(f1.z * inv, f1.w * inv);
            short8 b;
            __builtin_memcpy(&b, bw, 16);
            acc[t4] = __builtin_amdgcn_mfma_f32_16x16x32_bf16(a, b, acc[t4], 0, 0, 0);
        }
    }
    #pragma unroll
    for (int t4 = 0; t4 < 2; ++t4) {
        #pragma unroll
        for (int r = 0; r < 4; ++r) {
            const int o = m0 + wave * 16 + quad * 4 + r;
            const int n = n0 + t4 * 16 + l16;
            out[(size_t)o * 4096 + n] = acc[t4][r] + pb[o];
        }
    }
}

extern "C" void kernel_launch(void* const* d_in, const int* in_sizes, int n_in,
                              void* d_out, int out_size, void* d_ws, size_t ws_size,
                              hipStream_t stream) {
    const float* x      = (const float*)d_in[0];
    const float* qkv_w  = (const float*)d_in[1];
    const float* proj_w = (const float*)d_in[2];
    const float* proj_b = (const float*)d_in[3];
    float* out = (float*)d_out;                    // [256,4096] fp32

    char* B = (char*)d_ws;
    const size_t MB = 1u << 20;
    float* of32 = (float*)(B);                     // [4096][256] f32 unnormalized O (4 MB)
    float* lsum = (float*)(B + 4 * MB);            // [8][4096] f32 softmax denom (128 KB)
    unsigned short* qm = (unsigned short*)(B + 5 * MB);
    unsigned short* km = (unsigned short*)(B + 7 * MB);
    unsigned short* vt = (unsigned short*)(B + 9 * MB);   // ends at 11 MB

    hipMemsetAsync(B, 0, 4 * MB + 128 * 1024, stream);    // zero O/l accumulators
    k_qkv<<<dim3(64, 12), 256, 0, stream>>>(x, qkv_w, qm, km, vt);
    k_attn<<<dim3(128, 8), 256, 0, stream>>>(qm, km, vt, of32, lsum);
    k_proj<<<dim3(128, 4), 256, 0, stream>>>(of32, lsum, proj_w, proj_b, out);
}

// Round 19
// 134.055 us; speedup vs baseline: 1.0844x; 1.0844x over previous
//
#include <hip/hip_runtime.h>
#include <hip/hip_bf16.h>

typedef __attribute__((ext_vector_type(8))) short short8;
typedef __attribute__((ext_vector_type(4))) float floatx4;

#define L2E 1.4426950408889634f

#if __has_builtin(__builtin_amdgcn_exp2f)
#define EXP2(x) __builtin_amdgcn_exp2f(x)
#else
#define EXP2(x) exp2f(x)
#endif
#if __has_builtin(__builtin_amdgcn_rcpf)
#define RCP(x) __builtin_amdgcn_rcpf(x)
#else
#define RCP(x) (1.0f / (x))
#endif

static __device__ __forceinline__ unsigned short f2bf(float f) {
    unsigned int u = __builtin_bit_cast(unsigned int, f);
    u += 0x7fffu + ((u >> 16) & 1u);   // RNE
    return (unsigned short)(u >> 16);
}
static __device__ __forceinline__ unsigned int pk_bf16(float a, float b) {
    __hip_bfloat162 h2 = __float22bfloat162_rn(make_float2(a, b));   // v_cvt_pk_bf16_f32
    unsigned int u;
    __builtin_memcpy(&u, &h2, 4);     // low16 = a, high16 = b
    return u;
}

// ---------------- 1) QKV GEMM (R25 verbatim: vectorized staging, LDS-bounced V^T) ----------------
__global__ __launch_bounds__(256) void k_qkv(const float* __restrict__ x,
                                             const float* __restrict__ qw,
                                             unsigned short* __restrict__ qm,
                                             unsigned short* __restrict__ km,
                                             unsigned short* __restrict__ vt) {
    __shared__ __align__(16) unsigned short At[64][136];
    __shared__ __align__(16) unsigned short Wt[64][136];
    const int tid = threadIdx.x;
    const int wave = tid >> 6, lane = tid & 63;
    const int l16 = lane & 15, quad = lane >> 4;
    const int m0 = blockIdx.x * 64;
    const int o0 = blockIdx.y * 64;

    floatx4 acc[4] = {};
    for (int rnd = 0; rnd < 2; ++rnd) {
        const int cbase = rnd * 128;
        if (rnd) __syncthreads();
        {
            const int tok0 = (tid & 15) * 4;
            const int c0   = (tid >> 4) * 8;
            const float* xp = x + (size_t)(cbase + c0) * 4096 + m0 + tok0;
            float4 v[8];
            #pragma unroll
            for (int j = 0; j < 8; ++j)
                v[j] = *reinterpret_cast<const float4*>(xp + (size_t)j * 4096);
            #pragma unroll
            for (int t = 0; t < 4; ++t) {
                unsigned int d[4];
                d[0] = pk_bf16((&v[0].x)[t], (&v[1].x)[t]);
                d[1] = pk_bf16((&v[2].x)[t], (&v[3].x)[t]);
                d[2] = pk_bf16((&v[4].x)[t], (&v[5].x)[t]);
                d[3] = pk_bf16((&v[6].x)[t], (&v[7].x)[t]);
                __builtin_memcpy(&At[tok0 + t][c0], d, 16);
            }
        }
        {
            const int o_l = tid >> 2, cp = (tid & 3) * 32;
            const float4* wp = reinterpret_cast<const float4*>(
                qw + (size_t)(o0 + o_l) * 256 + cbase + cp);
            #pragma unroll
            for (int j = 0; j < 2; ++j) {
                const float4 g0 = wp[4 * j + 0], g1 = wp[4 * j + 1];
                const float4 g2 = wp[4 * j + 2], g3 = wp[4 * j + 3];
                unsigned int u[8];
                u[0] = pk_bf16(g0.x, g0.y); u[1] = pk_bf16(g0.z, g0.w);
                u[2] = pk_bf16(g1.x, g1.y); u[3] = pk_bf16(g1.z, g1.w);
                u[4] = pk_bf16(g2.x, g2.y); u[5] = pk_bf16(g2.z, g2.w);
                u[6] = pk_bf16(g3.x, g3.y); u[7] = pk_bf16(g3.z, g3.w);
                __builtin_memcpy(&Wt[o_l][cp + 16 * j], u, 32);
            }
        }
        __syncthreads();
        #pragma unroll
        for (int cc = 0; cc < 4; ++cc) {
            const int c0 = cc * 32 + quad * 8;
            const short8 a = *reinterpret_cast<const short8*>(&At[wave * 16 + l16][c0]);
            #pragma unroll
            for (int t4 = 0; t4 < 4; ++t4) {
                const short8 b = *reinterpret_cast<const short8*>(&Wt[t4 * 16 + l16][c0]);
                acc[t4] = __builtin_amdgcn_mfma_f32_16x16x32_bf16(a, b, acc[t4], 0, 0, 0);
            }
        }
    }

    const int s = o0 >> 8;   // block-uniform: 0=q, 1=k, 2=v
    if (s < 2) {
        const float qscale = 0.17677669529663687f * L2E;
        #pragma unroll
        for (int t4 = 0; t4 < 4; ++t4) {
            #pragma unroll
            for (int r = 0; r < 4; ++r) {
                const int n = m0 + wave * 16 + quad * 4 + r;
                const int o = o0 + t4 * 16 + l16;
                const int rem = o & 255, head = rem >> 5, t = rem & 31;
                if (s == 0)  qm[((size_t)head * 4096 + n) * 32 + t] = f2bf(acc[t4][r] * qscale);
                else         km[((size_t)head * 4096 + n) * 32 + t] = f2bf(acc[t4][r]);
            }
        }
    } else {
        __syncthreads();
        unsigned short (*Ct)[72] = reinterpret_cast<unsigned short(*)[72]>(&At[0][0]);
        #pragma unroll
        for (int t4 = 0; t4 < 4; ++t4) {
            unsigned int d2[2];
            d2[0] = pk_bf16(acc[t4][0], acc[t4][1]);
            d2[1] = pk_bf16(acc[t4][2], acc[t4][3]);
            __builtin_memcpy(&Ct[t4 * 16 + l16][wave * 16 + quad * 4], d2, 8);
        }
        __syncthreads();
        const int row = tid >> 2, col0 = (tid & 3) * 16;
        unsigned short* dst = vt + (size_t)(o0 - 512 + row) * 4096 + m0 + col0;
        const short8 ca = *reinterpret_cast<const short8*>(&Ct[row][col0]);
        const short8 cb = *reinterpret_cast<const short8*>(&Ct[row][col0 + 8]);
        *reinterpret_cast<short8*>(dst) = ca;
        *reinterpret_cast<short8*>(dst + 8) = cb;
    }
}

// ---------------- 2) flash attention: R32 verbatim (best: 58.0us attn / 134.7 total) ----------------
// R34: R33's KV-split + f32 atomic combine REGRESSED (attn 63.2us; WRITE_SIZE
// 2048->33024 KB -- device-scope f32 atomics generated ~33MB of HBM write
// traffic, far outweighing the occupancy gain 15->17.8%). Reverted to R32:
// 2 branch-free chains/phase + setprio + wave-uniform dead-tile skip, bf16 ao out.
__global__ __launch_bounds__(256, 2) void k_attn(const unsigned short* __restrict__ qm,
                                                 const unsigned short* __restrict__ km,
                                                 const unsigned short* __restrict__ vt,
                                                 unsigned short* __restrict__ ao) {
    const int h   = blockIdx.y;
    const int nq0 = blockIdx.x * 64;          // 64 q-rows per block (same dq for all)
    const int tid = threadIdx.x;
    const int wv  = tid >> 6;                 // wave owns q-tile nq0 + wv*16
    const int lane = tid & 63;
    const int l16 = lane & 15, quad = lane >> 4;
    const int nqw = nq0 + wv * 16;

    __shared__ __align__(16) unsigned short Kt[2][2][2048];   // [buf][slot][key*32+dim ^ swz]
    __shared__ __align__(16) unsigned short Vt[2][2][2048];   // [buf][slot][kg*256+dim*8 ^ swz]
    __shared__ __align__(16) unsigned short PT[4][2][16][72]; // [wave][slot][q][key] plain

    const short8 a_q = *reinterpret_cast<const short8*>(
        qm + ((size_t)h * 4096 + nqw + l16) * 32 + quad * 8);

    const int hq = (nqw >> 4) & 15;
    const int dq = nq0 >> 8;
    float dw2[4];
    #pragma unroll
    for (int r = 0; r < 4; ++r) {
        const float dw = (float)(quad * 4 + r - l16);
        dw2[r] = dw * dw;
    }

    const int dk_lo = (dq > 9) ? dq - 9 : 0;
    const int dk_hi = (dq < 6) ? dq + 9 : 15;
    const int NT = 4 * (dk_hi - dk_lo + 1);   // 40..64, divisible by 4

    const int skey = tid >> 2;
    const int sdo  = (tid & 3) * 8;
    const int sdim = tid >> 3;
    const int skg  = tid & 7;
    const unsigned short* ksrc = km + ((size_t)h << 17) + skey * 32 + sdo;
    const unsigned short* vsrc = vt + (((size_t)h * 32 + sdim) << 12) + skg * 8;
    const int kdst = (skey * 32 + sdo) ^ ((skey & 7) << 3);
    const int vdst = (skg * 256 + sdim * 8) ^ (skg << 3);

    float l_acc = 0.f;
    floatx4 o_acc[2][2] = {};                 // [slot][hf]

#define J0T(T) (((dk_lo + ((T) >> 2)) << 8) + (((T) & 3) << 6))

    short8 rK[2], rV[2];
#define LOAD2(TA, TB) {                                                   \
        const int ja_ = J0T(TA), jb_ = J0T(TB);                           \
        rK[0] = *reinterpret_cast<const short8*>(ksrc + (size_t)ja_ * 32);\
        rV[0] = *reinterpret_cast<const short8*>(vsrc + ja_);             \
        rK[1] = *reinterpret_cast<const short8*>(ksrc + (size_t)jb_ * 32);\
        rV[1] = *reinterpret_cast<const short8*>(vsrc + jb_);             \
    }
#define WRITE2(NB) {                                                      \
        *reinterpret_cast<short8*>(&Kt[NB][0][kdst]) = rK[0];             \
        *reinterpret_cast<short8*>(&Vt[NB][0][vdst]) = rV[0];             \
        *reinterpret_cast<short8*>(&Kt[NB][1][kdst]) = rK[1];             \
        *reinterpret_cast<short8*>(&Vt[NB][1][vdst]) = rV[1];             \
    }

// scalar thresholds for tile T (SALU; wave-uniform)
#define THR(T, TH) {                                                      \
        const int dk_ = dk_lo + ((T) >> 2), g_ = (T) & 3;                 \
        const int dd_ = dq - dk_;                                         \
        const int bb_ = 100 - dd_ * dd_;                                  \
        const int h0_ = hq - 4 * g_;                                      \
        TH[0] = bb_ - h0_ * h0_;                                          \
        TH[1] = bb_ - (h0_ - 1) * (h0_ - 1);                              \
        TH[2] = bb_ - (h0_ - 2) * (h0_ - 2);                              \
        TH[3] = bb_ - (h0_ - 3) * (h0_ - 3);                              \
    }

// branch-free S stage with precomputed thresholds (dead subtiles -> exact P=0)
#define SSTAGE(TH, CB, SL) {                                              \
        _Pragma("unroll")                                                 \
        for (int t4 = 0; t4 < 4; ++t4) {                                  \
            const short8 kf = *reinterpret_cast<const short8*>(           \
                &Kt[CB][SL][((t4 * 16 + l16) * 32 + quad * 8) ^ ((l16 & 7) << 3)]); \
            const floatx4 sf = __builtin_amdgcn_mfma_f32_16x16x32_bf16(   \
                kf, a_q, (floatx4){0.f, 0.f, 0.f, 0.f}, 0, 0, 0);         \
            const float thrf = (float)TH[t4];                             \
            const float p0 = (dw2[0] < thrf) ? EXP2(sf[0]) : 0.f;         \
            const float p1 = (dw2[1] < thrf) ? EXP2(sf[1]) : 0.f;         \
            const float p2 = (dw2[2] < thrf) ? EXP2(sf[2]) : 0.f;         \
            const float p3 = (dw2[3] < thrf) ? EXP2(sf[3]) : 0.f;         \
            l_acc += (p0 + p1) + (p2 + p3);                               \
            unsigned int pair_[2];                                        \
            pair_[0] = pk_bf16(p0, p1);                                   \
            pair_[1] = pk_bf16(p2, p3);                                   \
            __builtin_memcpy(&PT[wv][SL][l16][t4 * 16 + quad * 4], pair_, 8); \
        }                                                                 \
    }

#define PVST(CB, SL) {                                                    \
        _Pragma("unroll")                                                 \
        for (int kt = 0; kt < 2; ++kt) {                                  \
            const short8 b_p = *reinterpret_cast<const short8*>(          \
                &PT[wv][SL][l16][kt * 32 + quad * 8]);                    \
            const int kg = kt * 4 + quad;                                 \
            _Pragma("unroll")                                             \
            for (int hf = 0; hf < 2; ++hf) {                              \
                const short8 vf = *reinterpret_cast<const short8*>(       \
                    &Vt[CB][SL][(kg * 256 + (hf * 16 + l16) * 8) ^ (kg << 3)]); \
                o_acc[SL][hf] = __builtin_amdgcn_mfma_f32_16x16x32_bf16(  \
                    vf, b_p, o_acc[SL][hf], 0, 0, 0);                     \
            }                                                             \
        }                                                                 \
    }

    // prologue: tiles 0,1 -> buf0; tiles 2,3 -> regs
    LOAD2(0, 1)
    WRITE2(0)
    LOAD2(2, 3)
    __syncthreads();

    for (int t2 = 0; t2 < NT; t2 += 2) {
        const int cb = (t2 >> 1) & 1, nb = cb ^ 1;
        WRITE2(nb)                      // tiles t2+2, t2+3 (vmcnt waits here)
        {
            int ta = t2 + 4; if (ta >= NT) ta = NT - 1;
            int tb = t2 + 5; if (tb >= NT) tb = NT - 1;
            LOAD2(ta, tb)               // issue early; consumed next phase
        }
        int thA[4], thB[4];
        THR(t2, thA)
        THR(t2 + 1, thB)
        const bool liveA = (thA[0] > 0) | (thA[1] > 0) | (thA[2] > 0) | (thA[3] > 0);
        const bool liveB = (thB[0] > 0) | (thB[1] > 0) | (thB[2] > 0) | (thB[3] > 0);
        __builtin_amdgcn_s_setprio(1);  // T5: compute section wins SIMD arbitration
        if (liveA & liveB) {            // fast path: measured straight-line block
            SSTAGE(thA, cb, 0)
            SSTAGE(thB, cb, 1)
            PVST(cb, 0)
            PVST(cb, 1)
        } else if (liveA) {
            SSTAGE(thA, cb, 0)
            PVST(cb, 0)
        } else if (liveB) {
            SSTAGE(thB, cb, 1)
            PVST(cb, 1)
        }
        __builtin_amdgcn_s_setprio(0);
        __syncthreads();
    }
#undef PVST
#undef SSTAGE
#undef THR
#undef WRITE2
#undef LOAD2
#undef J0T

    // epilogue: waves own disjoint q-rows; direct write
    l_acc += __shfl_xor(l_acc, 16);
    l_acc += __shfl_xor(l_acc, 32);
    const float inv = RCP(l_acc);
    #pragma unroll
    for (int hf = 0; hf < 2; ++hf) {
        const floatx4 os = o_acc[0][hf] + o_acc[1][hf];
        unsigned int uu[2];
        uu[0] = pk_bf16(os[0] * inv, os[1] * inv);
        uu[1] = pk_bf16(os[2] * inv, os[3] * inv);
        __builtin_memcpy(ao + (size_t)(nqw + l16) * 256 + h * 32 + hf * 16 + quad * 4,
                         uu, 8);
    }
}

// ---------------- 3) proj GEMM + bias: all 16 B-fragments prefetched before the MFMA chain ----------------
// R34: proj's inner loop was 16 dependent global-load->MFMA steps (B from ao
// inline) -- ~16 exposed L2 round-trips per wave-tile at 2 blocks/CU. Two-stage:
// issue all 16 independent B loads (64 VGPR), single vmcnt drain, then 16
// back-to-back MFMAs from registers. Pt staging unchanged.
__global__ __launch_bounds__(256) void k_proj(const unsigned short* __restrict__ ao,
                                              const float* __restrict__ pw,
                                              const float* __restrict__ pb,
                                              float* __restrict__ out) {
    __shared__ __align__(16) unsigned short Pt[64][264];
    const int tid = threadIdx.x;
    const int wave = tid >> 6, lane = tid & 63;
    const int l16 = lane & 15, quad = lane >> 4;
    const int n0 = blockIdx.x * 32;
    const int m0 = blockIdx.y * 64;

    // stage 1a: issue all 16 B-fragment loads (independent, stay in flight)
    short8 bfrag[8][2];
    #pragma unroll
    for (int cc = 0; cc < 8; ++cc) {
        const int c0 = cc * 32 + quad * 8;
        #pragma unroll
        for (int t4 = 0; t4 < 2; ++t4)
            bfrag[cc][t4] = *reinterpret_cast<const short8*>(
                ao + (size_t)(n0 + t4 * 16 + l16) * 256 + c0);
    }

    // stage 1b: pw tile -> LDS (overlaps with B loads in flight)
    {
        const int o_l = tid >> 2, cp = (tid & 3) * 64;
        const float4* wp = reinterpret_cast<const float4*>(pw + (size_t)(m0 + o_l) * 256 + cp);
        #pragma unroll
        for (int j = 0; j < 4; ++j) {
            const float4 g0 = wp[4 * j + 0], g1 = wp[4 * j + 1];
            const float4 g2 = wp[4 * j + 2], g3 = wp[4 * j + 3];
            unsigned int u[8];
            u[0] = pk_bf16(g0.x, g0.y); u[1] = pk_bf16(g0.z, g0.w);
            u[2] = pk_bf16(g1.x, g1.y); u[3] = pk_bf16(g1.z, g1.w);
            u[4] = pk_bf16(g2.x, g2.y); u[5] = pk_bf16(g2.z, g2.w);
            u[6] = pk_bf16(g3.x, g3.y); u[7] = pk_bf16(g3.z, g3.w);
            __builtin_memcpy(&Pt[o_l][cp + 16 * j], u, 32);
        }
    }
    __syncthreads();

    // stage 2: 16 back-to-back MFMAs, B from registers, A from LDS
    floatx4 acc[2] = {};
    #pragma unroll
    for (int cc = 0; cc < 8; ++cc) {
        const int c0 = cc * 32 + quad * 8;
        const short8 a = *reinterpret_cast<const short8*>(&Pt[wave * 16 + l16][c0]);
        #pragma unroll
        for (int t4 = 0; t4 < 2; ++t4)
            acc[t4] = __builtin_amdgcn_mfma_f32_16x16x32_bf16(a, bfrag[cc][t4], acc[t4], 0, 0, 0);
    }
    #pragma unroll
    for (int t4 = 0; t4 < 2; ++t4) {
        #pragma unroll
        for (int r = 0; r < 4; ++r) {
            const int o = m0 + wave * 16 + quad * 4 + r;
            const int n = n0 + t4 * 16 + l16;
            out[(size_t)o * 4096 + n] = acc[t4][r] + pb[o];
        }
    }
}

extern "C" void kernel_launch(void* const* d_in, const int* in_sizes, int n_in,
                              void* d_out, int out_size, void* d_ws, size_t ws_size,
                              hipStream_t stream) {
    const float* x      = (const float*)d_in[0];
    const float* qkv_w  = (const float*)d_in[1];
    const float* proj_w = (const float*)d_in[2];
    const float* proj_b = (const float*)d_in[3];
    float* out = (float*)d_out;                    // [256,4096] fp32

    char* B = (char*)d_ws;
    const size_t MB = 1u << 20;
    unsigned short* ao = (unsigned short*)(B);
    unsigned short* qm = (unsigned short*)(B + 2 * MB);
    unsigned short* km = (unsigned short*)(B + 4 * MB);
    unsigned short* vt = (unsigned short*)(B + 6 * MB);

    k_qkv<<<dim3(64, 12), 256, 0, stream>>>(x, qkv_w, qm, km, vt);
    k_attn<<<dim3(64, 8), 256, 0, stream>>>(qm, km, vt, ao);
    k_proj<<<dim3(128, 4), 256, 0, stream>>>(ao, proj_w, proj_b, out);
}

// Round 20
// 132.975 us; speedup vs baseline: 1.0932x; 1.0081x over previous
//
#include <hip/hip_runtime.h>
#include <hip/hip_bf16.h>

typedef __attribute__((ext_vector_type(8))) short short8;
typedef __attribute__((ext_vector_type(4))) float floatx4;

#define L2E 1.4426950408889634f

#if __has_builtin(__builtin_amdgcn_exp2f)
#define EXP2(x) __builtin_amdgcn_exp2f(x)
#else
#define EXP2(x) exp2f(x)
#endif
#if __has_builtin(__builtin_amdgcn_rcpf)
#define RCP(x) __builtin_amdgcn_rcpf(x)
#else
#define RCP(x) (1.0f / (x))
#endif

static __device__ __forceinline__ unsigned short f2bf(float f) {
    unsigned int u = __builtin_bit_cast(unsigned int, f);
    u += 0x7fffu + ((u >> 16) & 1u);   // RNE
    return (unsigned short)(u >> 16);
}
static __device__ __forceinline__ unsigned int pk_bf16(float a, float b) {
    __hip_bfloat162 h2 = __float22bfloat162_rn(make_float2(a, b));   // v_cvt_pk_bf16_f32
    unsigned int u;
    __builtin_memcpy(&u, &h2, 4);     // low16 = a, high16 = b
    return u;
}

// ---------------- 1) QKV GEMM: o-tile 32, 6 blocks/CU ----------------
// R35: the ~77us non-attn pool is insensitive to micro-fixes (R25/R34) but closes
// arithmetically only if k_qkv is LATENCY-bound (~25-30us): two serial rounds of
// exposed global->LDS staging + 3 barriers at just 3 blocks/CU. Same medicine as
// attn: o-tile 64->32 (grid 64x24 = 1536 blocks), Wt[32][136], LDS 34.8->26.1KB ->
// 6 blocks/CU co-resident. Per-block MFMA halves; x-tile staged redundantly 2x
// (+48MB L3-resident traffic, cheap). Epilogues reworked for the 32-wide o-tile.
__global__ __launch_bounds__(256, 6) void k_qkv(const float* __restrict__ x,
                                                const float* __restrict__ qw,
                                                unsigned short* __restrict__ qm,
                                                unsigned short* __restrict__ km,
                                                unsigned short* __restrict__ vt) {
    __shared__ __align__(16) unsigned short At[64][136];
    __shared__ __align__(16) unsigned short Wt[32][136];
    const int tid = threadIdx.x;
    const int wave = tid >> 6, lane = tid & 63;
    const int l16 = lane & 15, quad = lane >> 4;
    const int m0 = blockIdx.x * 64;
    const int o0 = blockIdx.y * 32;

    floatx4 acc[2] = {};
    for (int rnd = 0; rnd < 2; ++rnd) {
        const int cbase = rnd * 128;
        if (rnd) __syncthreads();
        {
            const int tok0 = (tid & 15) * 4;
            const int c0   = (tid >> 4) * 8;
            const float* xp = x + (size_t)(cbase + c0) * 4096 + m0 + tok0;
            float4 v[8];
            #pragma unroll
            for (int j = 0; j < 8; ++j)
                v[j] = *reinterpret_cast<const float4*>(xp + (size_t)j * 4096);
            #pragma unroll
            for (int t = 0; t < 4; ++t) {
                unsigned int d[4];
                d[0] = pk_bf16((&v[0].x)[t], (&v[1].x)[t]);
                d[1] = pk_bf16((&v[2].x)[t], (&v[3].x)[t]);
                d[2] = pk_bf16((&v[4].x)[t], (&v[5].x)[t]);
                d[3] = pk_bf16((&v[6].x)[t], (&v[7].x)[t]);
                __builtin_memcpy(&At[tok0 + t][c0], d, 16);
            }
        }
        {
            // weight tile: 32 rows x 128 cols f32; thread = 16 consecutive floats
            const int o_l = tid >> 3, cp = (tid & 7) * 16;
            const float4* wp = reinterpret_cast<const float4*>(
                qw + (size_t)(o0 + o_l) * 256 + cbase + cp);
            const float4 g0 = wp[0], g1 = wp[1], g2 = wp[2], g3 = wp[3];
            unsigned int u[8];
            u[0] = pk_bf16(g0.x, g0.y); u[1] = pk_bf16(g0.z, g0.w);
            u[2] = pk_bf16(g1.x, g1.y); u[3] = pk_bf16(g1.z, g1.w);
            u[4] = pk_bf16(g2.x, g2.y); u[5] = pk_bf16(g2.z, g2.w);
            u[6] = pk_bf16(g3.x, g3.y); u[7] = pk_bf16(g3.z, g3.w);
            __builtin_memcpy(&Wt[o_l][cp], u, 32);
        }
        __syncthreads();
        #pragma unroll
        for (int cc = 0; cc < 4; ++cc) {
            const int c0 = cc * 32 + quad * 8;
            const short8 a = *reinterpret_cast<const short8*>(&At[wave * 16 + l16][c0]);
            #pragma unroll
            for (int t4 = 0; t4 < 2; ++t4) {
                const short8 b = *reinterpret_cast<const short8*>(&Wt[t4 * 16 + l16][c0]);
                acc[t4] = __builtin_amdgcn_mfma_f32_16x16x32_bf16(a, b, acc[t4], 0, 0, 0);
            }
        }
    }

    const int s = o0 >> 8;   // block-uniform: 0=q, 1=k, 2=v
    if (s < 2) {
        const float qscale = 0.17677669529663687f * L2E;
        #pragma unroll
        for (int t4 = 0; t4 < 2; ++t4) {
            #pragma unroll
            for (int r = 0; r < 4; ++r) {
                const int n = m0 + wave * 16 + quad * 4 + r;
                const int o = o0 + t4 * 16 + l16;
                const int rem = o & 255, head = rem >> 5, t = rem & 31;
                if (s == 0)  qm[((size_t)head * 4096 + n) * 32 + t] = f2bf(acc[t4][r] * qscale);
                else         km[((size_t)head * 4096 + n) * 32 + t] = f2bf(acc[t4][r]);
            }
        }
    } else {
        // V^T: bounce 32x64 tile through LDS (reuse At) then coalesced stores
        __syncthreads();
        unsigned short (*Ct)[72] = reinterpret_cast<unsigned short(*)[72]>(&At[0][0]);
        #pragma unroll
        for (int t4 = 0; t4 < 2; ++t4) {
            unsigned int d2[2];
            d2[0] = pk_bf16(acc[t4][0], acc[t4][1]);
            d2[1] = pk_bf16(acc[t4][2], acc[t4][3]);
            __builtin_memcpy(&Ct[t4 * 16 + l16][wave * 16 + quad * 4], d2, 8);
        }
        __syncthreads();
        const int row = tid >> 3, col0 = (tid & 7) * 8;
        unsigned short* dst = vt + (size_t)(o0 - 512 + row) * 4096 + m0 + col0;
        *reinterpret_cast<short8*>(dst) =
            *reinterpret_cast<const short8*>(&Ct[row][col0]);
    }
}

// ---------------- 2) flash attention: R32 verbatim (best: ~57us attn) ----------------
__global__ __launch_bounds__(256, 2) void k_attn(const unsigned short* __restrict__ qm,
                                                 const unsigned short* __restrict__ km,
                                                 const unsigned short* __restrict__ vt,
                                                 unsigned short* __restrict__ ao) {
    const int h   = blockIdx.y;
    const int nq0 = blockIdx.x * 64;          // 64 q-rows per block (same dq for all)
    const int tid = threadIdx.x;
    const int wv  = tid >> 6;                 // wave owns q-tile nq0 + wv*16
    const int lane = tid & 63;
    const int l16 = lane & 15, quad = lane >> 4;
    const int nqw = nq0 + wv * 16;

    __shared__ __align__(16) unsigned short Kt[2][2][2048];   // [buf][slot][key*32+dim ^ swz]
    __shared__ __align__(16) unsigned short Vt[2][2][2048];   // [buf][slot][kg*256+dim*8 ^ swz]
    __shared__ __align__(16) unsigned short PT[4][2][16][72]; // [wave][slot][q][key] plain

    const short8 a_q = *reinterpret_cast<const short8*>(
        qm + ((size_t)h * 4096 + nqw + l16) * 32 + quad * 8);

    const int hq = (nqw >> 4) & 15;
    const int dq = nq0 >> 8;
    float dw2[4];
    #pragma unroll
    for (int r = 0; r < 4; ++r) {
        const float dw = (float)(quad * 4 + r - l16);
        dw2[r] = dw * dw;
    }

    const int dk_lo = (dq > 9) ? dq - 9 : 0;
    const int dk_hi = (dq < 6) ? dq + 9 : 15;
    const int NT = 4 * (dk_hi - dk_lo + 1);   // 40..64, divisible by 4

    const int skey = tid >> 2;
    const int sdo  = (tid & 3) * 8;
    const int sdim = tid >> 3;
    const int skg  = tid & 7;
    const unsigned short* ksrc = km + ((size_t)h << 17) + skey * 32 + sdo;
    const unsigned short* vsrc = vt + (((size_t)h * 32 + sdim) << 12) + skg * 8;
    const int kdst = (skey * 32 + sdo) ^ ((skey & 7) << 3);
    const int vdst = (skg * 256 + sdim * 8) ^ (skg << 3);

    float l_acc = 0.f;
    floatx4 o_acc[2][2] = {};                 // [slot][hf]

#define J0T(T) (((dk_lo + ((T) >> 2)) << 8) + (((T) & 3) << 6))

    short8 rK[2], rV[2];
#define LOAD2(TA, TB) {                                                   \
        const int ja_ = J0T(TA), jb_ = J0T(TB);                           \
        rK[0] = *reinterpret_cast<const short8*>(ksrc + (size_t)ja_ * 32);\
        rV[0] = *reinterpret_cast<const short8*>(vsrc + ja_);             \
        rK[1] = *reinterpret_cast<const short8*>(ksrc + (size_t)jb_ * 32);\
        rV[1] = *reinterpret_cast<const short8*>(vsrc + jb_);             \
    }
#define WRITE2(NB) {                                                      \
        *reinterpret_cast<short8*>(&Kt[NB][0][kdst]) = rK[0];             \
        *reinterpret_cast<short8*>(&Vt[NB][0][vdst]) = rV[0];             \
        *reinterpret_cast<short8*>(&Kt[NB][1][kdst]) = rK[1];             \
        *reinterpret_cast<short8*>(&Vt[NB][1][vdst]) = rV[1];             \
    }

// scalar thresholds for tile T (SALU; wave-uniform)
#define THR(T, TH) {                                                      \
        const int dk_ = dk_lo + ((T) >> 2), g_ = (T) & 3;                 \
        const int dd_ = dq - dk_;                                         \
        const int bb_ = 100 - dd_ * dd_;                                  \
        const int h0_ = hq - 4 * g_;                                      \
        TH[0] = bb_ - h0_ * h0_;                                          \
        TH[1] = bb_ - (h0_ - 1) * (h0_ - 1);                              \
        TH[2] = bb_ - (h0_ - 2) * (h0_ - 2);                              \
        TH[3] = bb_ - (h0_ - 3) * (h0_ - 3);                              \
    }

// branch-free S stage with precomputed thresholds (dead subtiles -> exact P=0)
#define SSTAGE(TH, CB, SL) {                                              \
        _Pragma("unroll")                                                 \
        for (int t4 = 0; t4 < 4; ++t4) {                                  \
            const short8 kf = *reinterpret_cast<const short8*>(           \
                &Kt[CB][SL][((t4 * 16 + l16) * 32 + quad * 8) ^ ((l16 & 7) << 3)]); \
            const floatx4 sf = __builtin_amdgcn_mfma_f32_16x16x32_bf16(   \
                kf, a_q, (floatx4){0.f, 0.f, 0.f, 0.f}, 0, 0, 0);         \
            const float thrf = (float)TH[t4];                             \
            const float p0 = (dw2[0] < thrf) ? EXP2(sf[0]) : 0.f;         \
            const float p1 = (dw2[1] < thrf) ? EXP2(sf[1]) : 0.f;         \
            const float p2 = (dw2[2] < thrf) ? EXP2(sf[2]) : 0.f;         \
            const float p3 = (dw2[3] < thrf) ? EXP2(sf[3]) : 0.f;         \
            l_acc += (p0 + p1) + (p2 + p3);                               \
            unsigned int pair_[2];                                        \
            pair_[0] = pk_bf16(p0, p1);                                   \
            pair_[1] = pk_bf16(p2, p3);                                   \
            __builtin_memcpy(&PT[wv][SL][l16][t4 * 16 + quad * 4], pair_, 8); \
        }                                                                 \
    }

#define PVST(CB, SL) {                                                    \
        _Pragma("unroll")                                                 \
        for (int kt = 0; kt < 2; ++kt) {                                  \
            const short8 b_p = *reinterpret_cast<const short8*>(          \
                &PT[wv][SL][l16][kt * 32 + quad * 8]);                    \
            const int kg = kt * 4 + quad;                                 \
            _Pragma("unroll")                                             \
            for (int hf = 0; hf < 2; ++hf) {                              \
                const short8 vf = *reinterpret_cast<const short8*>(       \
                    &Vt[CB][SL][(kg * 256 + (hf * 16 + l16) * 8) ^ (kg << 3)]); \
                o_acc[SL][hf] = __builtin_amdgcn_mfma_f32_16x16x32_bf16(  \
                    vf, b_p, o_acc[SL][hf], 0, 0, 0);                     \
            }                                                             \
        }                                                                 \
    }

    // prologue: tiles 0,1 -> buf0; tiles 2,3 -> regs
    LOAD2(0, 1)
    WRITE2(0)
    LOAD2(2, 3)
    __syncthreads();

    for (int t2 = 0; t2 < NT; t2 += 2) {
        const int cb = (t2 >> 1) & 1, nb = cb ^ 1;
        WRITE2(nb)                      // tiles t2+2, t2+3 (vmcnt waits here)
        {
            int ta = t2 + 4; if (ta >= NT) ta = NT - 1;
            int tb = t2 + 5; if (tb >= NT) tb = NT - 1;
            LOAD2(ta, tb)               // issue early; consumed next phase
        }
        int thA[4], thB[4];
        THR(t2, thA)
        THR(t2 + 1, thB)
        const bool liveA = (thA[0] > 0) | (thA[1] > 0) | (thA[2] > 0) | (thA[3] > 0);
        const bool liveB = (thB[0] > 0) | (thB[1] > 0) | (thB[2] > 0) | (thB[3] > 0);
        __builtin_amdgcn_s_setprio(1);  // T5: compute section wins SIMD arbitration
        if (liveA & liveB) {            // fast path: measured straight-line block
            SSTAGE(thA, cb, 0)
            SSTAGE(thB, cb, 1)
            PVST(cb, 0)
            PVST(cb, 1)
        } else if (liveA) {
            SSTAGE(thA, cb, 0)
            PVST(cb, 0)
        } else if (liveB) {
            SSTAGE(thB, cb, 1)
            PVST(cb, 1)
        }
        __builtin_amdgcn_s_setprio(0);
        __syncthreads();
    }
#undef PVST
#undef SSTAGE
#undef THR
#undef WRITE2
#undef LOAD2
#undef J0T

    // epilogue: waves own disjoint q-rows; direct write
    l_acc += __shfl_xor(l_acc, 16);
    l_acc += __shfl_xor(l_acc, 32);
    const float inv = RCP(l_acc);
    #pragma unroll
    for (int hf = 0; hf < 2; ++hf) {
        const floatx4 os = o_acc[0][hf] + o_acc[1][hf];
        unsigned int uu[2];
        uu[0] = pk_bf16(os[0] * inv, os[1] * inv);
        uu[1] = pk_bf16(os[2] * inv, os[3] * inv);
        __builtin_memcpy(ao + (size_t)(nqw + l16) * 256 + h * 32 + hf * 16 + quad * 4,
                         uu, 8);
    }
}

// ---------------- 3) proj GEMM + bias (R34 verbatim: B-fragments prefetched) ----------------
__global__ __launch_bounds__(256) void k_proj(const unsigned short* __restrict__ ao,
                                              const float* __restrict__ pw,
                                              const float* __restrict__ pb,
                                              float* __restrict__ out) {
    __shared__ __align__(16) unsigned short Pt[64][264];
    const int tid = threadIdx.x;
    const int wave = tid >> 6, lane = tid & 63;
    const int l16 = lane & 15, quad = lane >> 4;
    const int n0 = blockIdx.x * 32;
    const int m0 = blockIdx.y * 64;

    // stage 1a: issue all 16 B-fragment loads (independent, stay in flight)
    short8 bfrag[8][2];
    #pragma unroll
    for (int cc = 0; cc < 8; ++cc) {
        const int c0 = cc * 32 + quad * 8;
        #pragma unroll
        for (int t4 = 0; t4 < 2; ++t4)
            bfrag[cc][t4] = *reinterpret_cast<const short8*>(
                ao + (size_t)(n0 + t4 * 16 + l16) * 256 + c0);
    }

    // stage 1b: pw tile -> LDS (overlaps with B loads in flight)
    {
        const int o_l = tid >> 2, cp = (tid & 3) * 64;
        const float4* wp = reinterpret_cast<const float4*>(pw + (size_t)(m0 + o_l) * 256 + cp);
        #pragma unroll
        for (int j = 0; j < 4; ++j) {
            const float4 g0 = wp[4 * j + 0], g1 = wp[4 * j + 1];
            const float4 g2 = wp[4 * j + 2], g3 = wp[4 * j + 3];
            unsigned int u[8];
            u[0] = pk_bf16(g0.x, g0.y); u[1] = pk_bf16(g0.z, g0.w);
            u[2] = pk_bf16(g1.x, g1.y); u[3] = pk_bf16(g1.z, g1.w);
            u[4] = pk_bf16(g2.x, g2.y); u[5] = pk_bf16(g2.z, g2.w);
            u[6] = pk_bf16(g3.x, g3.y); u[7] = pk_bf16(g3.z, g3.w);
            __builtin_memcpy(&Pt[o_l][cp + 16 * j], u, 32);
        }
    }
    __syncthreads();

    // stage 2: 16 back-to-back MFMAs, B from registers, A from LDS
    floatx4 acc[2] = {};
    #pragma unroll
    for (int cc = 0; cc < 8; ++cc) {
        const int c0 = cc * 32 + quad * 8;
        const short8 a = *reinterpret_cast<const short8*>(&Pt[wave * 16 + l16][c0]);
        #pragma unroll
        for (int t4 = 0; t4 < 2; ++t4)
            acc[t4] = __builtin_amdgcn_mfma_f32_16x16x32_bf16(a, bfrag[cc][t4], acc[t4], 0, 0, 0);
    }
    #pragma unroll
    for (int t4 = 0; t4 < 2; ++t4) {
        #pragma unroll
        for (int r = 0; r < 4; ++r) {
            const int o = m0 + wave * 16 + quad * 4 + r;
            const int n = n0 + t4 * 16 + l16;
            out[(size_t)o * 4096 + n] = acc[t4][r] + pb[o];
        }
    }
}

extern "C" void kernel_launch(void* const* d_in, const int* in_sizes, int n_in,
                              void* d_out, int out_size, void* d_ws, size_t ws_size,
                              hipStream_t stream) {
    const float* x      = (const float*)d_in[0];
    const float* qkv_w  = (const float*)d_in[1];
    const float* proj_w = (const float*)d_in[2];
    const float* proj_b = (const float*)d_in[3];
    float* out = (float*)d_out;                    // [256,4096] fp32

    char* B = (char*)d_ws;
    const size_t MB = 1u << 20;
    unsigned short* ao = (unsigned short*)(B);
    unsigned short* qm = (unsigned short*)(B + 2 * MB);
    unsigned short* km = (unsigned short*)(B + 4 * MB);
    unsigned short* vt = (unsigned short*)(B + 6 * MB);

    k_qkv<<<dim3(64, 24), 256, 0, stream>>>(x, qkv_w, qm, km, vt);
    k_attn<<<dim3(64, 8), 256, 0, stream>>>(qm, km, vt, ao);
    k_proj<<<dim3(128, 4), 256, 0, stream>>>(ao, proj_w, proj_b, out);
}